// Round 1
// baseline (1573.915 us; speedup 1.0000x reference)
//
#include <hip/hip_runtime.h>
#include <math.h>

#define NN 20000
#define H 256
#define R 64
#define EE 320000
#define LN_EPS 1e-5f

__device__ __forceinline__ float silu_f(float x) { return x / (1.0f + __expf(-x)); }

// ---------------------------------------------------------------------------
// K1: fused LayerNorm + Q/K/V projections.  16 nodes per 256-thread block.
// ---------------------------------------------------------------------------
__global__ __launch_bounds__(256) void k_ln_qkv(
    const float* __restrict__ x, const float* __restrict__ g, const float* __restrict__ b,
    const float* __restrict__ Wq, const float* __restrict__ bq,
    const float* __restrict__ Wk, const float* __restrict__ bk,
    const float* __restrict__ Wv, const float* __restrict__ bv,
    float* __restrict__ q, float* __restrict__ k, float* __restrict__ v)
{
    __shared__ float xn[16][H];          // 16 KB
    const int t  = threadIdx.x;
    const int n0 = blockIdx.x * 16;

    #pragma unroll
    for (int i = 0; i < 16; ++i) xn[i][t] = x[(size_t)(n0 + i) * H + t];
    __syncthreads();

    // LayerNorm: 16 lanes per node, shuffle-reduce.
    const int n = t >> 4, s = t & 15;
    float sum = 0.f, sq = 0.f;
    #pragma unroll
    for (int j = 0; j < 16; ++j) { float val = xn[n][s + 16 * j]; sum += val; sq += val * val; }
    #pragma unroll
    for (int off = 8; off; off >>= 1) { sum += __shfl_xor(sum, off); sq += __shfl_xor(sq, off); }
    const float mu  = sum * (1.0f / H);
    const float var = sq * (1.0f / H) - mu * mu;
    const float rs  = rsqrtf(var + LN_EPS);
    #pragma unroll
    for (int j = 0; j < 16; ++j) {
        int c = s + 16 * j;
        float val = xn[n][c];
        xn[n][c] = (val - mu) * rs * g[c] + b[c];
    }
    __syncthreads();

    // thread t owns output column h = t for all 16 nodes, 3 matrices fused
    float aq[16], ak[16], av[16];
    #pragma unroll
    for (int i = 0; i < 16; ++i) { aq[i] = 0.f; ak[i] = 0.f; av[i] = 0.f; }
    const float* wqr = Wq + (size_t)t * H;
    const float* wkr = Wk + (size_t)t * H;
    const float* wvr = Wv + (size_t)t * H;
    for (int kk = 0; kk < H; kk += 4) {
        const float4 wq4 = *(const float4*)(wqr + kk);
        const float4 wk4 = *(const float4*)(wkr + kk);
        const float4 wv4 = *(const float4*)(wvr + kk);
        #pragma unroll
        for (int i = 0; i < 16; ++i) {
            const float4 x4 = *(const float4*)&xn[i][kk];
            aq[i] += wq4.x * x4.x + wq4.y * x4.y + wq4.z * x4.z + wq4.w * x4.w;
            ak[i] += wk4.x * x4.x + wk4.y * x4.y + wk4.z * x4.z + wk4.w * x4.w;
            av[i] += wv4.x * x4.x + wv4.y * x4.y + wv4.z * x4.z + wv4.w * x4.w;
        }
    }
    const float bqv = bq[t], bkv = bk[t], bvv = bv[t];
    #pragma unroll
    for (int i = 0; i < 16; ++i) {
        q[(size_t)(n0 + i) * H + t] = aq[i] + bqv;
        k[(size_t)(n0 + i) * H + t] = ak[i] + bkv;
        v[(size_t)(n0 + i) * H + t] = av[i] + bvv;
    }
}

// ---------------------------------------------------------------------------
// K2: fused edge kernel. 64 edges per 256-thread block.
//   pass A (x2 h-halves): dk = silu(ea @ WdkT + bdk); attn_raw += sum_h q_i k_j dk
//   attn = silu(attn_raw) * cosine_cutoff(w)
//   pass B (x2 h-halves): dv = silu(ea @ WdvT + bdv); atomicAdd agg[dst] += v_j*dv*attn
// Weight half [64r][128h] transposed into LDS, reloaded from L2 per pass/half.
// ---------------------------------------------------------------------------
__global__ __launch_bounds__(256) void k_edge(
    const float* __restrict__ q, const float* __restrict__ k, const float* __restrict__ v,
    const int* __restrict__ ei, const float* __restrict__ ew, const float* __restrict__ ea,
    const float* __restrict__ Wdk, const float* __restrict__ bdk,
    const float* __restrict__ Wdv, const float* __restrict__ bdv,
    float* __restrict__ agg)
{
    __shared__ float ea_s[64][R];     // 16 KB
    __shared__ float w_s[R][128];     // 32 KB (one h-half of WdkT/WdvT)
    __shared__ float attn_s[64];
    __shared__ int   src_s[64], dst_s[64];
    __shared__ float cut_s[64];

    const int t  = threadIdx.x;
    const int eb = blockIdx.x * 64;

    #pragma unroll
    for (int i = 0; i < 16; ++i) {
        int flat = i * 256 + t;
        ea_s[flat >> 6][flat & 63] = ea[(size_t)eb * R + flat];
    }
    if (t < 64) {
        src_s[t] = ei[eb + t];
        dst_s[t] = ei[EE + eb + t];
        float r = ew[eb + t];
        cut_s[t] = (r < 5.0f) ? 0.5f * (__cosf(r * 0.6283185307f) + 1.0f) : 0.0f;
        attn_s[t] = 0.f;
    }

    const int tx = t & 31, ty = t >> 5;
    const int h0 = tx * 4, e0 = ty * 8;

    // ---------------- pass A: attention logits ----------------
    for (int hh = 0; hh < 2; ++hh) {
        __syncthreads();   // ea/meta ready (iter0); prior w_s readers done (iter1)
        {   // load WdkT half: w_s[r][hl] = Wdk[(hh*128+hl)*R + r]
            const int hl = t & 127, r0 = (t >> 7) * 32;
            const float* sp = Wdk + (size_t)(hh * 128 + hl) * R + r0;
            #pragma unroll
            for (int j = 0; j < 32; ++j) w_s[r0 + j][hl] = sp[j];
        }
        __syncthreads();

        float acc[8][4];
        const float4 bi = *(const float4*)(bdk + hh * 128 + h0);
        #pragma unroll
        for (int i = 0; i < 8; ++i) { acc[i][0] = bi.x; acc[i][1] = bi.y; acc[i][2] = bi.z; acc[i][3] = bi.w; }

        for (int r4 = 0; r4 < R; r4 += 4) {
            const float4 w0 = *(const float4*)&w_s[r4 + 0][h0];
            const float4 w1 = *(const float4*)&w_s[r4 + 1][h0];
            const float4 w2 = *(const float4*)&w_s[r4 + 2][h0];
            const float4 w3 = *(const float4*)&w_s[r4 + 3][h0];
            #pragma unroll
            for (int i = 0; i < 8; ++i) {
                const float4 a = *(const float4*)&ea_s[e0 + i][r4];
                acc[i][0] += a.x * w0.x + a.y * w1.x + a.z * w2.x + a.w * w3.x;
                acc[i][1] += a.x * w0.y + a.y * w1.y + a.z * w2.y + a.w * w3.y;
                acc[i][2] += a.x * w0.z + a.y * w1.z + a.z * w2.z + a.w * w3.z;
                acc[i][3] += a.x * w0.w + a.y * w1.w + a.z * w2.w + a.w * w3.w;
            }
        }
        #pragma unroll
        for (int i = 0; i < 8; ++i) {
            const int d = dst_s[e0 + i], s = src_s[e0 + i];
            const float4 qi = *(const float4*)(q + (size_t)d * H + hh * 128 + h0);
            const float4 kj = *(const float4*)(k + (size_t)s * H + hh * 128 + h0);
            float part = qi.x * kj.x * silu_f(acc[i][0]) + qi.y * kj.y * silu_f(acc[i][1])
                       + qi.z * kj.z * silu_f(acc[i][2]) + qi.w * kj.w * silu_f(acc[i][3]);
            #pragma unroll
            for (int off = 16; off; off >>= 1) part += __shfl_xor(part, off);
            if (tx == 0) attn_s[e0 + i] += part;   // same thread both halves: no race
        }
    }
    __syncthreads();
    if (t < 64) attn_s[t] = silu_f(attn_s[t]) * cut_s[t];

    // ---------------- pass B: messages + scatter ----------------
    for (int hh = 0; hh < 2; ++hh) {
        __syncthreads();   // attn finalized (iter0); prior w_s readers done (iter1)
        {
            const int hl = t & 127, r0 = (t >> 7) * 32;
            const float* sp = Wdv + (size_t)(hh * 128 + hl) * R + r0;
            #pragma unroll
            for (int j = 0; j < 32; ++j) w_s[r0 + j][hl] = sp[j];
        }
        __syncthreads();

        float acc[8][4];
        const float4 bi = *(const float4*)(bdv + hh * 128 + h0);
        #pragma unroll
        for (int i = 0; i < 8; ++i) { acc[i][0] = bi.x; acc[i][1] = bi.y; acc[i][2] = bi.z; acc[i][3] = bi.w; }

        for (int r4 = 0; r4 < R; r4 += 4) {
            const float4 w0 = *(const float4*)&w_s[r4 + 0][h0];
            const float4 w1 = *(const float4*)&w_s[r4 + 1][h0];
            const float4 w2 = *(const float4*)&w_s[r4 + 2][h0];
            const float4 w3 = *(const float4*)&w_s[r4 + 3][h0];
            #pragma unroll
            for (int i = 0; i < 8; ++i) {
                const float4 a = *(const float4*)&ea_s[e0 + i][r4];
                acc[i][0] += a.x * w0.x + a.y * w1.x + a.z * w2.x + a.w * w3.x;
                acc[i][1] += a.x * w0.y + a.y * w1.y + a.z * w2.y + a.w * w3.y;
                acc[i][2] += a.x * w0.z + a.y * w1.z + a.z * w2.z + a.w * w3.z;
                acc[i][3] += a.x * w0.w + a.y * w1.w + a.z * w2.w + a.w * w3.w;
            }
        }
        #pragma unroll
        for (int i = 0; i < 8; ++i) {
            const int d = dst_s[e0 + i], s = src_s[e0 + i];
            const float a = attn_s[e0 + i];
            const float4 vj = *(const float4*)(v + (size_t)s * H + hh * 128 + h0);
            float* dp = agg + (size_t)d * H + hh * 128 + h0;
            atomicAdd(dp + 0, vj.x * silu_f(acc[i][0]) * a);
            atomicAdd(dp + 1, vj.y * silu_f(acc[i][1]) * a);
            atomicAdd(dp + 2, vj.z * silu_f(acc[i][2]) * a);
            atomicAdd(dp + 3, vj.w * silu_f(acc[i][3]) * a);
        }
    }
}

// ---------------------------------------------------------------------------
// K3: out = x + agg @ Wo^T + bo.  16 nodes per 256-thread block.
// ---------------------------------------------------------------------------
__global__ __launch_bounds__(256) void k_out(
    const float* __restrict__ aggm, const float* __restrict__ Wo, const float* __restrict__ bo,
    const float* __restrict__ x, float* __restrict__ out)
{
    __shared__ float ag[16][H];
    const int t  = threadIdx.x;
    const int n0 = blockIdx.x * 16;
    #pragma unroll
    for (int i = 0; i < 16; ++i) ag[i][t] = aggm[(size_t)(n0 + i) * H + t];
    __syncthreads();

    float acc[16];
    #pragma unroll
    for (int i = 0; i < 16; ++i) acc[i] = 0.f;
    const float* wor = Wo + (size_t)t * H;
    for (int kk = 0; kk < H; kk += 4) {
        const float4 w4 = *(const float4*)(wor + kk);
        #pragma unroll
        for (int i = 0; i < 16; ++i) {
            const float4 a4 = *(const float4*)&ag[i][kk];
            acc[i] += w4.x * a4.x + w4.y * a4.y + w4.z * a4.z + w4.w * a4.w;
        }
    }
    const float bov = bo[t];
    #pragma unroll
    for (int i = 0; i < 16; ++i)
        out[(size_t)(n0 + i) * H + t] = x[(size_t)(n0 + i) * H + t] + acc[i] + bov;
}

extern "C" void kernel_launch(void* const* d_in, const int* in_sizes, int n_in,
                              void* d_out, int out_size, void* d_ws, size_t ws_size,
                              hipStream_t stream) {
    const float* x   = (const float*)d_in[0];
    const int*   ei  = (const int*)d_in[1];
    const float* ew  = (const float*)d_in[2];
    const float* ea  = (const float*)d_in[3];
    const float* g   = (const float*)d_in[4];
    const float* b   = (const float*)d_in[5];
    const float* Wq  = (const float*)d_in[6];  const float* bq  = (const float*)d_in[7];
    const float* Wk  = (const float*)d_in[8];  const float* bk  = (const float*)d_in[9];
    const float* Wv  = (const float*)d_in[10]; const float* bv  = (const float*)d_in[11];
    const float* Wo  = (const float*)d_in[12]; const float* bo  = (const float*)d_in[13];
    const float* Wdk = (const float*)d_in[14]; const float* bdk = (const float*)d_in[15];
    const float* Wdv = (const float*)d_in[16]; const float* bdv = (const float*)d_in[17];

    float* q   = (float*)d_ws;
    float* k   = q + (size_t)NN * H;
    float* v   = k + (size_t)NN * H;
    float* agg = v + (size_t)NN * H;

    hipMemsetAsync(agg, 0, (size_t)NN * H * sizeof(float), stream);
    k_ln_qkv<<<NN / 16, 256, 0, stream>>>(x, g, b, Wq, bq, Wk, bk, Wv, bv, q, k, v);
    k_edge<<<EE / 64, 256, 0, stream>>>(q, k, v, ei, ew, ea, Wdk, bdk, Wdv, bdv, agg);
    k_out<<<NN / 16, 256, 0, stream>>>(agg, Wo, bo, x, (float*)d_out);
}